// Round 7
// baseline (79.587 us; speedup 1.0000x reference)
//
#include <hip/hip_runtime.h>
#include <hip/hip_bf16.h>
#include <math.h>

#define DIM 256
#define BB 1024
#define KK 128
#define EPB 4   // elements per block; grid = BB/EPB = 256 = one block per CU

typedef __attribute__((ext_vector_type(8))) short short8;
typedef __attribute__((ext_vector_type(4))) float float4v;

__device__ __forceinline__ float dot4(const float4 a, const float4 b) {
    return a.x*b.x + a.y*b.y + a.z*b.z + a.w*b.w;
}

// two f32 -> packed bf16x2 bits (RNE); lowers to v_cvt_pk_bf16_f32
__device__ __forceinline__ unsigned bf2bits(float a, float b) {
    float2 t; t.x = a; t.y = b;
    __hip_bfloat162 h = __float22bfloat162_rn(t);
    unsigned u; __builtin_memcpy(&u, &h, 4);
    return u;
}
__device__ __forceinline__ float bf2f(unsigned short v) {
    unsigned u = ((unsigned)v) << 16;
    float f; __builtin_memcpy(&f, &u, 4);
    return f;
}

// swizzled element offset within a 128x256 bf16 tile:
// XOR element bits [5:3] with row&7 -> 16-lane column-slice reads become
// 2-way bank aliased (free) instead of 16-way. Write and read use the same
// involution, so reads return true k-indices (A=B Gram symmetry preserved).
__device__ __forceinline__ int swz(int row, int col) {
    return (row << 8) + (col ^ ((row & 7) << 3));
}

// score element: combine rowpart halves (s_diff) + fpart (f_diff). wave 0 only.
__device__ __forceinline__ void score_one(const float* rp, const unsigned short* fp,
                                          int lane, float* out)
{
    float stot = 0.f;
    #pragma unroll
    for (int rr = 0; rr < 2; ++rr) {
        const int row = lane * 2 + rr;
        const float4 pa = *(const float4*)(rp + row * 8);
        const float4 pb = *(const float4*)(rp + row * 8 + 4);
        const float s   = pa.x + pb.x;
        const float a2  = pa.y + pb.y;
        const float a3  = pa.z + pb.z;
        const float fia = pa.w + pb.w;
        // sum (adj-p)^2 = sum(adj) - invS*(2 sum(adj e) - invS sum(e^2))
        const float invS = __builtin_amdgcn_rcpf(s);
        stot += sqrtf(fmaxf(fia - invS * (2.f * a2 - invS * a3), 0.f));
    }
    float4 d = make_float4(0.f, 0.f, 0.f, 0.f);
    #pragma unroll
    for (int j = 0; j < 8; ++j) {
        const ushort4 u = *(const ushort4*)(fp + j * DIM + 4 * lane);
        d.x += bf2f(u.x); d.y += bf2f(u.y);
        d.z += bf2f(u.z); d.w += bf2f(u.w);
    }
    const float inv = 1.f / 128.f;
    d.x *= inv; d.y *= inv; d.z *= inv; d.w *= inv;
    float q2 = dot4(d, d);
    #pragma unroll
    for (int m = 1; m < 64; m <<= 1) {
        stot += __shfl_xor(stot, m);
        q2   += __shfl_xor(q2,   m);
    }
    if (lane == 0) *out = stot * (1.f / 128.f) + sqrtf(q2);
}

// Producer-consumer: waves 8-15 gather element i+1 (L3 traffic) while
// waves 0-7 compute element i (MFMA + HBM gumbel/adj stream). One block/CU.
__global__ __attribute__((amdgpu_flat_work_group_size(1024, 1024),
                          amdgpu_waves_per_eu(4, 4)))
void fused_main(const float* __restrict__ feature,
                const float* __restrict__ text,
                const float* __restrict__ virt,
                const float* __restrict__ gumbel,
                const int*   __restrict__ ego,
                const int*   __restrict__ adj,
                float*       __restrict__ score_raw)
{
    __shared__ unsigned short tbs[2][KK * DIM];   // 131072 B, double-buffered
    __shared__ float rowpart[2][KK][8];           // 8192 B  ({s,a2,a3,fia} x 2 halves)
    __shared__ unsigned short fpart[3][8][DIM];   // 12288 B (bf16 f_diff partials)

    const int tid  = threadIdx.x;
    const int wave = tid >> 6;
    const int lane = tid & 63;
    const int b0   = blockIdx.x * EPB;
    const int g    = lane >> 4;
    const int c    = lane & 15;

    // virtual row + ||v||^2 (gather waves use these)
    const float4 vm = ((const float4*)virt)[lane];
    float vv2 = dot4(vm, vm);
    #pragma unroll
    for (int m = 1; m < 64; m <<= 1) vv2 += __shfl_xor(vv2, m);

    #pragma unroll
    for (int i = 0; i <= EPB; ++i) {
        if (wave < 8) {
            // ---- score element i-2 (overlapped; wave 0 only)
            if (i >= 2 && wave == 0)
                score_one(&rowpart[(i - 2) & 1][0][0], &fpart[(i - 2) % 3][0][0],
                          lane, &score_raw[b0 + i - 2]);

            // ---- compute element i-1 from tbs[(i-1)&1]
            if (i >= 1) {
                const int e = b0 + (i - 1);
                const unsigned short* tb = &tbs[(i - 1) & 1][0];
                float* rp = &rowpart[(i - 1) & 1][0][0];
                const int base = wave * 16;
                const float* gr = gumbel + ((size_t)e * KK + base + g * 4) * KK + c;
                const int*   ar = adj    + ((size_t)e * KK + base + g * 4) * KK + c;

                #pragma unroll
                for (int h = 0; h < 2; ++h) {
                    // prime stream row 0 of this half (covered by the q-loop)
                    int a_in[4]; float g_in[4];
                    #pragma unroll
                    for (int t = 0; t < 4; ++t) {
                        a_in[t] = __builtin_nontemporal_load(ar + h * 64 + t * 16);
                        g_in[t] = __builtin_nontemporal_load(gr + h * 64 + t * 16);
                    }
                    float4v acc[4];
                    #pragma unroll
                    for (int t = 0; t < 4; ++t) acc[t] = (float4v){0.f, 0.f, 0.f, 0.f};
                    #pragma unroll
                    for (int q = 0; q < 8; ++q) {
                        const int dq = q * 32 + g * 8;
                        const short8 afr = *(const short8*)&tb[swz(base + c, dq)];
                        #pragma unroll
                        for (int t = 0; t < 4; ++t) {
                            const short8 bfr =
                                *(const short8*)&tb[swz(h * 64 + t * 16 + c, dq)];
                            acc[t] = __builtin_amdgcn_mfma_f32_16x16x32_bf16(
                                afr, bfr, acc[t], 0, 0, 0);
                        }
                    }
                    // softmax partials, 1-row stream lookahead
                    #pragma unroll
                    for (int r = 0; r < 4; ++r) {
                        int av[4]; float gv[4];
                        #pragma unroll
                        for (int t = 0; t < 4; ++t) { av[t] = a_in[t]; gv[t] = g_in[t]; }
                        if (r < 3) {
                            #pragma unroll
                            for (int t = 0; t < 4; ++t) {
                                a_in[t] = __builtin_nontemporal_load(
                                    ar + (r + 1) * KK + h * 64 + t * 16);
                                g_in[t] = __builtin_nontemporal_load(
                                    gr + (r + 1) * KK + h * 64 + t * 16);
                            }
                        }
                        float s = 0.f, a2 = 0.f, a3 = 0.f, fia = 0.f;
                        #pragma unroll
                        for (int t = 0; t < 4; ++t) {
                            const float vt = acc[t][r] - 0.5f + gv[t];
                            const float et = __expf(vt);   // |vt| small: fp32-safe
                            s  += et;
                            a3 += et * et;
                            a2 += av[t] ? et : 0.f;
                            fia += av[t] ? 1.f : 0.f;
                        }
                        #pragma unroll
                        for (int m = 1; m < 16; m <<= 1) {
                            s   += __shfl_xor(s,   m);
                            a2  += __shfl_xor(a2,  m);
                            a3  += __shfl_xor(a3,  m);
                            fia += __shfl_xor(fia, m);
                        }
                        if (c == 0) {
                            float4 pk; pk.x = s; pk.y = a2; pk.z = a3; pk.w = fia;
                            *(float4*)(rp + (base + g * 4 + r) * 8 + h * 4) = pk;
                        }
                    }
                }
            }
        } else {
            // ---- gather element i into tbs[i&1]
            if (i < EPB) {
                const int e  = b0 + i;
                const int gw = wave - 8;
                unsigned short* tb = &tbs[i & 1][0];
                const int* ego_b = ego + (size_t)e * KK + gw * 16;
                int eidx[16];
                #pragma unroll
                for (int k = 0; k < 16; ++k) eidx[k] = ego_b[k];

                float4 fdv = make_float4(0.f, 0.f, 0.f, 0.f);
                float4 pt[2], pf[2];
                #pragma unroll
                for (int p = 0; p < 2; ++p) {
                    pt[p] = ((const float4*)(text    + (size_t)eidx[p] * DIM))[lane];
                    pf[p] = ((const float4*)(feature + (size_t)eidx[p] * DIM))[lane];
                }
                #pragma unroll
                for (int k = 0; k < 16; ++k) {
                    const int sl = k & 1;
                    const float4 ct = pt[sl], cf = pf[sl];
                    if (k < 14) {
                        pt[sl] = ((const float4*)(text    + (size_t)eidx[k + 2] * DIM))[lane];
                        pf[sl] = ((const float4*)(feature + (size_t)eidx[k + 2] * DIM))[lane];
                    }
                    float st = dot4(ct, ct), sf = dot4(cf, cf), sv = dot4(ct, vm);
                    #pragma unroll
                    for (int m = 1; m < 64; m <<= 1) {
                        st += __shfl_xor(st, m);
                        sf += __shfl_xor(sf, m);
                        sv += __shfl_xor(sv, m);
                    }
                    const float inv_ne = __builtin_amdgcn_rsqf(fmaxf(st, 1e-24f));
                    const float inv_nf = __builtin_amdgcn_rsqf(fmaxf(sf, 1e-24f));
                    // ||emb - v||^2 = 1 + ||v||^2 - 2 (t.v)/||t||
                    const float nw2    = fmaxf(1.f + vv2 - 2.f * sv * inv_ne, 1e-24f);
                    const float inv_nt = __builtin_amdgcn_rsqf(nw2);
                    const float e0 = ct.x * inv_ne, e1 = ct.y * inv_ne;
                    const float e2 = ct.z * inv_ne, e3 = ct.w * inv_ne;
                    fdv.x += cf.x * inv_nf - e0;
                    fdv.y += cf.y * inv_nf - e1;
                    fdv.z += cf.z * inv_nf - e2;
                    fdv.w += cf.w * inv_nf - e3;
                    uint2 pk;
                    pk.x = bf2bits((e0 - vm.x) * inv_nt, (e1 - vm.y) * inv_nt);
                    pk.y = bf2bits((e2 - vm.z) * inv_nt, (e3 - vm.w) * inv_nt);
                    *(uint2*)&tb[swz(gw * 16 + k, 4 * lane)] = pk;
                }
                uint2 fpk;
                fpk.x = bf2bits(fdv.x, fdv.y);
                fpk.y = bf2bits(fdv.z, fdv.w);
                *(uint2*)&fpart[i % 3][gw][4 * lane] = fpk;
            }
        }
        __syncthreads();
    }

    // epilogue: score last element
    if (wave == 0)
        score_one(&rowpart[(EPB - 1) & 1][0][0], &fpart[(EPB - 1) % 3][0][0],
                  lane, &score_raw[b0 + EPB - 1]);
}

__global__ __launch_bounds__(1024) void finalize(
    const float* __restrict__ score_raw,
    const int*   __restrict__ label,
    float*       __restrict__ out)
{
    __shared__ float wmin[16], wmax[16], wsum[16];
    const int tid = threadIdx.x;
    const float s = score_raw[tid];
    float mn = s, mx = s;
    #pragma unroll
    for (int m = 1; m < 64; m <<= 1) {
        mn = fminf(mn, __shfl_xor(mn, m));
        mx = fmaxf(mx, __shfl_xor(mx, m));
    }
    if ((tid & 63) == 0) { wmin[tid >> 6] = mn; wmax[tid >> 6] = mx; }
    __syncthreads();
    float gmn = wmin[0], gmx = wmax[0];
    #pragma unroll
    for (int w = 1; w < 16; ++w) {
        gmn = fminf(gmn, wmin[w]);
        gmx = fmaxf(gmx, wmax[w]);
    }
    const float score = (s - gmn) / (gmx - gmn);
    out[tid] = score;

    const float y  = (float)label[tid];
    const float sc = fminf(fmaxf(score, 1e-7f), 1.f - 1e-7f);
    float term = -(y * logf(sc) + (1.f - y) * log1pf(-sc));
    #pragma unroll
    for (int m = 1; m < 64; m <<= 1) term += __shfl_xor(term, m);
    if ((tid & 63) == 0) wsum[tid >> 6] = term;
    __syncthreads();
    if (tid == 0) {
        float tot = 0.f;
        #pragma unroll
        for (int w = 0; w < 16; ++w) tot += wsum[w];
        out[BB] = tot / (1024.f * 1024.f);
    }
}

extern "C" void kernel_launch(void* const* d_in, const int* in_sizes, int n_in,
                              void* d_out, int out_size, void* d_ws, size_t ws_size,
                              hipStream_t stream) {
    const float* feature = (const float*)d_in[0];
    const float* text    = (const float*)d_in[1];
    const float* virt    = (const float*)d_in[2];
    const float* gumbel  = (const float*)d_in[3];
    const int*   ego     = (const int*)d_in[4];
    const int*   adj     = (const int*)d_in[5];
    const int*   label   = (const int*)d_in[6];
    float* out       = (float*)d_out;
    float* score_raw = (float*)d_ws;

    fused_main<<<BB / EPB, 1024, 0, stream>>>(feature, text, virt, gumbel, ego, adj,
                                              score_raw);
    finalize<<<1, 1024, 0, stream>>>(score_raw, label, out);
}

// Round 8
// 70.106 us; speedup vs baseline: 1.1352x; 1.1352x over previous
//
#include <hip/hip_runtime.h>
#include <hip/hip_bf16.h>
#include <math.h>

#define DIM 256
#define BB 1024
#define KK 128
#define PITCH 264   // bf16 elements per LDS row: 528 B, 16B-aligned rows

typedef __attribute__((ext_vector_type(8))) short short8;
typedef __attribute__((ext_vector_type(4))) float float4v;

__device__ __forceinline__ float dot4(const float4 a, const float4 b) {
    return a.x*b.x + a.y*b.y + a.z*b.z + a.w*b.w;
}

// two f32 -> packed bf16x2 bits (RNE); lowers to v_cvt_pk_bf16_f32
__device__ __forceinline__ unsigned bf2bits(float a, float b) {
    float2 t; t.x = a; t.y = b;
    __hip_bfloat162 h = __float22bfloat162_rn(t);
    unsigned u; __builtin_memcpy(&u, &h, 4);
    return u;
}

// x + row_ror<CTRL>(x): VALU-only cross-lane add within a 16-lane DPP row.
template<int CTRL>
__device__ __forceinline__ float addror(float x) {
    int r = __builtin_amdgcn_update_dpp(0, __float_as_int(x), CTRL, 0xF, 0xF, true);
    return x + __int_as_float(r);
}
// sum over each 16-lane group; every lane gets its group's total. Pure VALU.
__device__ __forceinline__ float sum16dpp(float x) {
    x = addror<0x121>(x);   // row_ror:1
    x = addror<0x122>(x);   // row_ror:2
    x = addror<0x124>(x);   // row_ror:4
    x = addror<0x128>(x);   // row_ror:8
    return x;
}
// full 64-lane sum: 4 VALU-DPP steps + 2 cross-group shuffles.
__device__ __forceinline__ float sum64dpp(float x) {
    x = sum16dpp(x);
    x += __shfl_xor(x, 16);
    x += __shfl_xor(x, 32);
    return x;
}

// One block per batch element. 512 threads = 8 waves (the config the
// allocator gives a full 64-VGPR budget; 1024-thr blocks got 32 + spills).
__global__ __launch_bounds__(512, 4) void fused_main(
    const float* __restrict__ feature,
    const float* __restrict__ text,
    const float* __restrict__ virt,
    const float* __restrict__ gumbel,
    const int*   __restrict__ ego,
    const int*   __restrict__ adj,
    float*       __restrict__ score_raw)
{
    __shared__ unsigned short tbs[KK * PITCH];   // 67584 B
    __shared__ float fpart[8][DIM];              // 8192 B
    __shared__ float rowpart[KK][8];             // 4096 B ({s,a2,a3,fia} x 2 halves)
    __shared__ float spart[2];

    const int b    = blockIdx.x;
    const int tid  = threadIdx.x;
    const int wave = tid >> 6;
    const int lane = tid & 63;

    const float4 vm = ((const float4*)virt)[lane];
    const float vv2 = sum64dpp(dot4(vm, vm));    // ||v||^2, all lanes

    const int* ego_b = ego + b * KK;
    const int  base  = wave * 16;

    float4 fdv = make_float4(0.f, 0.f, 0.f, 0.f);

    // ---- Phase A: wave owns rows base..base+15; 4 rows per batch.
    // 8 loads issued back-to-back, 12 independent DPP reduction chains.
    #pragma unroll
    for (int bt = 0; bt < 4; ++bt) {
        const int r0 = base + bt * 4;
        const int e0i = ego_b[r0 + 0], e1i = ego_b[r0 + 1];
        const int e2i = ego_b[r0 + 2], e3i = ego_b[r0 + 3];
        const float4 T0 = ((const float4*)(text + (size_t)e0i * DIM))[lane];
        const float4 T1 = ((const float4*)(text + (size_t)e1i * DIM))[lane];
        const float4 T2 = ((const float4*)(text + (size_t)e2i * DIM))[lane];
        const float4 T3 = ((const float4*)(text + (size_t)e3i * DIM))[lane];
        const float4 F0 = ((const float4*)(feature + (size_t)e0i * DIM))[lane];
        const float4 F1 = ((const float4*)(feature + (size_t)e1i * DIM))[lane];
        const float4 F2 = ((const float4*)(feature + (size_t)e2i * DIM))[lane];
        const float4 F3 = ((const float4*)(feature + (size_t)e3i * DIM))[lane];

        float st0 = dot4(T0, T0), sv0 = dot4(T0, vm), sf0 = dot4(F0, F0);
        float st1 = dot4(T1, T1), sv1 = dot4(T1, vm), sf1 = dot4(F1, F1);
        float st2 = dot4(T2, T2), sv2 = dot4(T2, vm), sf2 = dot4(F2, F2);
        float st3 = dot4(T3, T3), sv3 = dot4(T3, vm), sf3 = dot4(F3, F3);

        st0 = sum64dpp(st0); sv0 = sum64dpp(sv0); sf0 = sum64dpp(sf0);
        st1 = sum64dpp(st1); sv1 = sum64dpp(sv1); sf1 = sum64dpp(sf1);
        st2 = sum64dpp(st2); sv2 = sum64dpp(sv2); sf2 = sum64dpp(sf2);
        st3 = sum64dpp(st3); sv3 = sum64dpp(sv3); sf3 = sum64dpp(sf3);

        // ||emb - v||^2 = 1 + ||v||^2 - 2 (t.v)/||t||
        #define NORMROW(Tj, Fj, stj, sfj, svj, ROW)                              \
        {                                                                        \
            const float inv_ne = __builtin_amdgcn_rsqf(fmaxf(stj, 1e-24f));      \
            const float inv_nf = __builtin_amdgcn_rsqf(fmaxf(sfj, 1e-24f));      \
            const float nw2    = fmaxf(1.f + vv2 - 2.f * svj * inv_ne, 1e-24f);  \
            const float inv_nt = __builtin_amdgcn_rsqf(nw2);                     \
            const float e0 = Tj.x * inv_ne, e1 = Tj.y * inv_ne;                  \
            const float e2 = Tj.z * inv_ne, e3 = Tj.w * inv_ne;                  \
            fdv.x += Fj.x * inv_nf - e0;  fdv.y += Fj.y * inv_nf - e1;           \
            fdv.z += Fj.z * inv_nf - e2;  fdv.w += Fj.w * inv_nf - e3;           \
            uint2 pk;                                                            \
            pk.x = bf2bits((e0 - vm.x) * inv_nt, (e1 - vm.y) * inv_nt);          \
            pk.y = bf2bits((e2 - vm.z) * inv_nt, (e3 - vm.w) * inv_nt);          \
            *(uint2*)&tbs[(ROW) * PITCH + 4 * lane] = pk;                        \
        }
        NORMROW(T0, F0, st0, sf0, sv0, r0 + 0)
        NORMROW(T1, F1, st1, sf1, sv1, r0 + 1)
        NORMROW(T2, F2, st2, sf2, sv2, r0 + 2)
        NORMROW(T3, F3, st3, sf3, sv3, r0 + 3)
        #undef NORMROW
    }
    *(float4*)&fpart[wave][4 * lane] = fdv;

    __syncthreads();

    // ---- Phase B: wave = 16-row strip; columns in two half passes.
    const int g = lane >> 4;   // 0..3
    const int c = lane & 15;

    #pragma unroll
    for (int h = 0; h < 2; ++h) {
        float4v acc[4];
        #pragma unroll
        for (int t = 0; t < 4; ++t) acc[t] = (float4v){0.f, 0.f, 0.f, 0.f};

        #pragma unroll
        for (int q = 0; q < 8; ++q) {
            const int dq = q * 32 + g * 8;
            const short8 afr = *(const short8*)&tbs[(base + c) * PITCH + dq];
            #pragma unroll
            for (int t = 0; t < 4; ++t) {
                const short8 bfr = *(const short8*)&tbs[(h * 64 + t * 16 + c) * PITCH + dq];
                acc[t] = __builtin_amdgcn_mfma_f32_16x16x32_bf16(afr, bfr, acc[t], 0, 0, 0);
            }
        }

        const float* gr = gumbel + ((size_t)b * KK + base + g * 4) * KK + h * 64 + c;
        const int*   ar = adj    + ((size_t)b * KK + base + g * 4) * KK + h * 64 + c;

        // softmax partials per row; 16-lane DPP trees (no DS ops).
        // No max-subtract needed: |sim-0.5+gumbel| <= ~14, fp32-safe.
        #pragma unroll
        for (int r = 0; r < 4; ++r) {
            int av0 = __builtin_nontemporal_load(ar + r * KK);
            int av1 = __builtin_nontemporal_load(ar + r * KK + 16);
            int av2 = __builtin_nontemporal_load(ar + r * KK + 32);
            int av3 = __builtin_nontemporal_load(ar + r * KK + 48);
            float gv0 = __builtin_nontemporal_load(gr + r * KK);
            float gv1 = __builtin_nontemporal_load(gr + r * KK + 16);
            float gv2 = __builtin_nontemporal_load(gr + r * KK + 32);
            float gv3 = __builtin_nontemporal_load(gr + r * KK + 48);

            const float et0 = __expf(acc[0][r] - 0.5f + gv0);
            const float et1 = __expf(acc[1][r] - 0.5f + gv1);
            const float et2 = __expf(acc[2][r] - 0.5f + gv2);
            const float et3 = __expf(acc[3][r] - 0.5f + gv3);

            float s   = et0 + et1 + et2 + et3;
            float a3  = et0*et0 + et1*et1 + et2*et2 + et3*et3;
            float a2  = (av0 ? et0 : 0.f) + (av1 ? et1 : 0.f)
                      + (av2 ? et2 : 0.f) + (av3 ? et3 : 0.f);
            float fia = (av0 ? 1.f : 0.f) + (av1 ? 1.f : 0.f)
                      + (av2 ? 1.f : 0.f) + (av3 ? 1.f : 0.f);

            s   = sum16dpp(s);
            a2  = sum16dpp(a2);
            a3  = sum16dpp(a3);
            fia = sum16dpp(fia);

            if (c == 0) {
                float4 pk4; pk4.x = s; pk4.y = a2; pk4.z = a3; pk4.w = fia;
                *(float4*)&rowpart[base + g * 4 + r][h * 4] = pk4;
            }
        }
    }

    __syncthreads();

    // combine halves: threads 0..127 own one row each (waves 0,1 fully active)
    if (tid < KK) {
        const float4 pa = *(const float4*)&rowpart[tid][0];
        const float4 pb = *(const float4*)&rowpart[tid][4];
        const float s   = pa.x + pb.x;
        const float a2  = pa.y + pb.y;
        const float a3  = pa.z + pb.z;
        const float fia = pa.w + pb.w;
        // sum (adj-p)^2 = sum(adj) - invS*(2 sum(adj e) - invS sum(e^2))
        const float invS = __builtin_amdgcn_rcpf(s);
        float sq = sqrtf(fmaxf(fia - invS * (2.f * a2 - invS * a3), 0.f));
        sq = sum64dpp(sq);
        if (lane == 0) spart[wave] = sq;   // wave 0 or 1
    }

    __syncthreads();

    if (wave == 0) {
        float4 d = make_float4(0.f, 0.f, 0.f, 0.f);
        #pragma unroll
        for (int j = 0; j < 8; ++j) {
            const float4 p = *(const float4*)&fpart[j][4 * lane];
            d.x += p.x; d.y += p.y; d.z += p.z; d.w += p.w;
        }
        const float inv = 1.f / 128.f;
        d.x *= inv; d.y *= inv; d.z *= inv; d.w *= inv;
        const float q2 = sum64dpp(dot4(d, d));
        if (lane == 0)
            score_raw[b] = (spart[0] + spart[1]) * (1.f / 128.f) + sqrtf(q2);
    }
}

__global__ __launch_bounds__(1024) void finalize(
    const float* __restrict__ score_raw,
    const int*   __restrict__ label,
    float*       __restrict__ out)
{
    __shared__ float wmin[16], wmax[16], wsum[16];
    const int tid = threadIdx.x;
    const float s = score_raw[tid];
    float mn = s, mx = s;
    #pragma unroll
    for (int m = 1; m < 64; m <<= 1) {
        mn = fminf(mn, __shfl_xor(mn, m));
        mx = fmaxf(mx, __shfl_xor(mx, m));
    }
    if ((tid & 63) == 0) { wmin[tid >> 6] = mn; wmax[tid >> 6] = mx; }
    __syncthreads();
    float gmn = wmin[0], gmx = wmax[0];
    #pragma unroll
    for (int w = 1; w < 16; ++w) {
        gmn = fminf(gmn, wmin[w]);
        gmx = fmaxf(gmx, wmax[w]);
    }
    const float score = (s - gmn) / (gmx - gmn);
    out[tid] = score;

    const float y  = (float)label[tid];
    const float sc = fminf(fmaxf(score, 1e-7f), 1.f - 1e-7f);
    float term = -(y * logf(sc) + (1.f - y) * log1pf(-sc));
    #pragma unroll
    for (int m = 1; m < 64; m <<= 1) term += __shfl_xor(term, m);
    if ((tid & 63) == 0) wsum[tid >> 6] = term;
    __syncthreads();
    if (tid == 0) {
        float tot = 0.f;
        #pragma unroll
        for (int w = 0; w < 16; ++w) tot += wsum[w];
        out[BB] = tot / (1024.f * 1024.f);
    }
}

extern "C" void kernel_launch(void* const* d_in, const int* in_sizes, int n_in,
                              void* d_out, int out_size, void* d_ws, size_t ws_size,
                              hipStream_t stream) {
    const float* feature = (const float*)d_in[0];
    const float* text    = (const float*)d_in[1];
    const float* virt    = (const float*)d_in[2];
    const float* gumbel  = (const float*)d_in[3];
    const int*   ego     = (const int*)d_in[4];
    const int*   adj     = (const int*)d_in[5];
    const int*   label   = (const int*)d_in[6];
    float* out       = (float*)d_out;
    float* score_raw = (float*)d_ws;

    fused_main<<<BB, 512, 0, stream>>>(feature, text, virt, gumbel, ego, adj, score_raw);
    finalize<<<1, 1024, 0, stream>>>(score_raw, label, out);
}